// Round 4
// baseline (101.230 us; speedup 1.0000x reference)
//
#include <hip/hip_runtime.h>

#define NUM_CLASSES 32
#define NBINS (NUM_CLASSES * NUM_CLASSES)   // 1024
#define BLOCK 256
#define GRID1 2048                          // 8 blocks/CU resident -> 32 waves/CU
#define GRID2 NUM_CLASSES                   // one block per output row
#define PK_PER_PART (NBINS / 2)             // 512 packed u16-pair uints per partial

// Stage 1: per-block private LDS histogram. Each block handles exactly
// n/GRID1 = 4096 elements, so every per-block bin count < 2^16 -> partials
// are stored as packed u16 pairs (2 KB/block, halving ws traffic vs u32).
// Counts ALL pixels unconditionally (bin = yt*32+yp in [0,1024)); the yt==0
// mask is applied in stage 2 by zeroing row 0 (reference: w=0 there).
__global__ __launch_bounds__(BLOCK) void confmat_partial(
    const int* __restrict__ y_true,
    const int* __restrict__ y_pred,
    unsigned int* __restrict__ ws,   // GRID1 x 512 packed uints
    int n)
{
    __shared__ unsigned int hist[NBINS];
    #pragma unroll
    for (int i = threadIdx.x; i < NBINS; i += BLOCK) hist[i] = 0u;
    __syncthreads();

    const int tid    = blockIdx.x * BLOCK + threadIdx.x;
    const int stride = GRID1 * BLOCK;
    const int n4 = n >> 2;
    const int4* __restrict__ t4 = (const int4*)y_true;
    const int4* __restrict__ p4 = (const int4*)y_pred;

    int i = tid;
    // 8 independent int4 loads in flight before any LDS op. For n = 8M this
    // covers every element in exactly one iteration (16 elems/thread).
    for (; i + 3 * stride < n4; i += 4 * stride) {
        int4 a0 = t4[i];              int4 b0 = p4[i];
        int4 a1 = t4[i + stride];     int4 b1 = p4[i + stride];
        int4 a2 = t4[i + 2 * stride]; int4 b2 = p4[i + 2 * stride];
        int4 a3 = t4[i + 3 * stride]; int4 b3 = p4[i + 3 * stride];
        atomicAdd(&hist[(a0.x << 5) | b0.x], 1u);
        atomicAdd(&hist[(a0.y << 5) | b0.y], 1u);
        atomicAdd(&hist[(a0.z << 5) | b0.z], 1u);
        atomicAdd(&hist[(a0.w << 5) | b0.w], 1u);
        atomicAdd(&hist[(a1.x << 5) | b1.x], 1u);
        atomicAdd(&hist[(a1.y << 5) | b1.y], 1u);
        atomicAdd(&hist[(a1.z << 5) | b1.z], 1u);
        atomicAdd(&hist[(a1.w << 5) | b1.w], 1u);
        atomicAdd(&hist[(a2.x << 5) | b2.x], 1u);
        atomicAdd(&hist[(a2.y << 5) | b2.y], 1u);
        atomicAdd(&hist[(a2.z << 5) | b2.z], 1u);
        atomicAdd(&hist[(a2.w << 5) | b2.w], 1u);
        atomicAdd(&hist[(a3.x << 5) | b3.x], 1u);
        atomicAdd(&hist[(a3.y << 5) | b3.y], 1u);
        atomicAdd(&hist[(a3.z << 5) | b3.z], 1u);
        atomicAdd(&hist[(a3.w << 5) | b3.w], 1u);
    }
    for (; i < n4; i += stride) {
        int4 a = t4[i]; int4 b = p4[i];
        atomicAdd(&hist[(a.x << 5) | b.x], 1u);
        atomicAdd(&hist[(a.y << 5) | b.y], 1u);
        atomicAdd(&hist[(a.z << 5) | b.z], 1u);
        atomicAdd(&hist[(a.w << 5) | b.w], 1u);
    }
    // Scalar tail (n not divisible by 4).
    for (int j = (n4 << 2) + tid; j < n; j += stride) {
        atomicAdd(&hist[(y_true[j] << 5) | y_pred[j]], 1u);
    }

    __syncthreads();

    // Flush as packed u16 pairs: thread t covers bins [4t, 4t+4) -> one uint2
    // store (8 B/lane, coalesced). Counts <= 4096 so no truncation.
    const int t = threadIdx.x;
    uint2 pk;
    pk.x = hist[4 * t + 0] | (hist[4 * t + 1] << 16);
    pk.y = hist[4 * t + 2] | (hist[4 * t + 3] << 16);
    ((uint2*)(ws + (size_t)blockIdx.x * PK_PER_PART))[t] = pk;
}

// Stage 2: block b sums row b (32 bins = 16 packed uints = 4 uint4) across all
// GRID1 partials and writes it with plain stores. Block 0 writes zeros (the
// yt==0 mask). No memset node, no global atomics anywhere.
__global__ __launch_bounds__(BLOCK) void confmat_reduce(
    const unsigned int* __restrict__ ws,
    float* __restrict__ out)
{
    __shared__ unsigned int sums[NUM_CLASSES];
    if (threadIdx.x < NUM_CLASSES) sums[threadIdx.x] = 0u;
    __syncthreads();

    const int q   = threadIdx.x & 3;          // uint4 within the row (8 bins)
    const int c   = threadIdx.x >> 2;         // 0..63: chunk of partials
    const int row = blockIdx.x;
    const uint4* __restrict__ w4 = (const uint4*)ws;

    unsigned int s[8] = {0u, 0u, 0u, 0u, 0u, 0u, 0u, 0u};
    #pragma unroll 8
    for (int k = 0; k < GRID1 / 64; ++k) {    // 32 partials per chunk
        int p = c * (GRID1 / 64) + k;
        uint4 v = w4[p * (PK_PER_PART / 4) + row * 4 + q];
        s[0] += v.x & 0xFFFFu; s[1] += v.x >> 16;
        s[2] += v.y & 0xFFFFu; s[3] += v.y >> 16;
        s[4] += v.z & 0xFFFFu; s[5] += v.z >> 16;
        s[6] += v.w & 0xFFFFu; s[7] += v.w >> 16;
    }
    #pragma unroll
    for (int j = 0; j < 8; ++j) atomicAdd(&sums[q * 8 + j], s[j]);
    __syncthreads();

    if (threadIdx.x < NUM_CLASSES) {
        float v = (row == 0) ? 0.0f : (float)sums[threadIdx.x];
        out[row * NUM_CLASSES + threadIdx.x] = v;
    }
}

extern "C" void kernel_launch(void* const* d_in, const int* in_sizes, int n_in,
                              void* d_out, int out_size, void* d_ws, size_t ws_size,
                              hipStream_t stream) {
    const int* y_true = (const int*)d_in[0];
    const int* y_pred = (const int*)d_in[1];
    float* out = (float*)d_out;
    unsigned int* ws = (unsigned int*)d_ws;    // needs GRID1*2KB = 4 MB
    int n = in_sizes[0];

    confmat_partial<<<GRID1, BLOCK, 0, stream>>>(y_true, y_pred, ws, n);
    confmat_reduce<<<GRID2, BLOCK, 0, stream>>>(ws, out);
}